// Round 10
// baseline (99.491 us; speedup 1.0000x reference)
//
#include <hip/hip_runtime.h>
#include <hip/hip_fp16.h>
#include <math.h>

// B=8, C=64, H=W=64, O=128, K=3, N=9, stride=1, pad=1
// ws layout (8.61 MB):
//   xTh  @ 0        : fp16 hi(x) [8][4096 pix][64 c] = 4,194,304 B
//   xTl  @ 4194304  : fp16 lo(x) [8][4096 pix][64 c] = 4,194,304 B
//   WtH  @ 8388608  : fp16 [9][128 o][64 c]          =   147,456 B
//   WtSh @ 8536064  : fp16 [9][32 ch][64 c]          =    36,864 B
//   WtSl @ 8572928  : fp16 [9][32 ch][64 c]          =    36,864 B

typedef _Float16 half8_t __attribute__((ext_vector_type(8)));
typedef float f32x4 __attribute__((ext_vector_type(4)));

// ---------------------------------------------------------------------------
// k_pre: blocks 0..511  : x (B,C,H,W) f32 -> xTh/xTl (B,HW,C) split fp16
//        blocks 512..871: conv_w -> WtH ; shift/mod weights -> WtSh/WtSl
// ---------------------------------------------------------------------------
__global__ __launch_bounds__(256) void k_pre(const float* __restrict__ x,
                                             const float* __restrict__ cw,
                                             const float* __restrict__ shift_w,
                                             const float* __restrict__ mod_w,
                                             __half* __restrict__ xTh,
                                             __half* __restrict__ xTl,
                                             __half* __restrict__ WtH,
                                             __half* __restrict__ WtSh,
                                             __half* __restrict__ WtSl) {
    __shared__ float tile[64][65];
    int bid = blockIdx.x;
    int t = threadIdx.x;
    if (bid < 512) {
        int b = bid >> 6, pt = bid & 63;
        int lane = t & 63, cq = t >> 6;
        const float* xb = x + ((size_t)b << 18);
#pragma unroll
        for (int r = 0; r < 16; ++r) {
            int c = cq * 16 + r;
            tile[c][lane] = xb[((size_t)c << 12) + pt * 64 + lane];
        }
        __syncthreads();
        int p = t >> 2, qc = t & 3;
        __align__(16) _Float16 hh[16];
        __align__(16) _Float16 ll[16];
#pragma unroll
        for (int k = 0; k < 16; ++k) {
            float v = tile[qc * 16 + k][p];
            _Float16 h = (_Float16)v;
            hh[k] = h;
            ll[k] = (_Float16)(v - (float)h);
        }
        size_t off = ((size_t)b << 18) + (size_t)(pt * 64 + p) * 64 + qc * 16;
        ((uint4*)(xTh + off))[0] = ((uint4*)hh)[0];
        ((uint4*)(xTh + off))[1] = ((uint4*)hh)[1];
        ((uint4*)(xTl + off))[0] = ((uint4*)ll)[0];
        ((uint4*)(xTl + off))[1] = ((uint4*)ll)[1];
    } else {
        int u = (bid - 512) * 256 + t;
        if (u < 73728) {
            int c = u & 63;
            int o = (u >> 6) & 127;
            int n = u >> 13;
            WtH[u] = __float2half_rn(cw[(o * 64 + c) * 9 + n]);
        } else {
            int v = u - 73728;
            if (v < 18432) {
                int c = v & 63;
                int ch = (v >> 6) & 31;
                int tap = v >> 11;
                float w = 0.f;
                if (ch < 18) w = shift_w[(ch * 64 + c) * 9 + tap];
                else if (ch < 27) w = mod_w[((ch - 18) * 64 + c) * 9 + tap];
                _Float16 h = (_Float16)w;
                _Float16 lo = (_Float16)(w - (float)h);
                WtSh[v] = *(__half*)&h;
                WtSl[v] = *(__half*)&lo;
            }
        }
    }
}

// ---------------------------------------------------------------------------
// k_dual: 2-wave blocks; block = 16 pixels, wave = 16 pix x 64 outputs.
//   grid 2048 x 128 thr -> 4096 waves = 16/CU = 4/SIMD (2x R9's TLP).
//   Phase A: stage1 conv split by c-half across the 2 waves (54 MFMA each),
//            partials summed in LDS at record time. 2 barriers total, both
//            BEFORE any phase-B loads (no vmcnt drain of prefetches).
//   Phase B: barrier-free; per tap: issue 8 B-loads -> combine prev gathers
//            (VALU hides B latency) -> re-issue gathers for n+1 (same regs)
//            -> 8 MFMA. acc = 16 pix x 64 o.
// ---------------------------------------------------------------------------
__global__ __launch_bounds__(128, 4) void k_dual(
    const __half* __restrict__ xTh, const __half* __restrict__ xTl,
    const __half* __restrict__ WtH, const __half* __restrict__ WtSh,
    const __half* __restrict__ WtSl, const float* __restrict__ shift_b,
    const float* __restrict__ mod_b, float* __restrict__ out) {
    __shared__ float Cw[2][16][36];   // per-wave stage1 partials (c-halves)
    __shared__ uint4 recA[9][16];     // per-pixel records: w0,w1,mod,pad

    int t = threadIdx.x;
    int l = t & 63;
    int w = t >> 6;                   // wave 0/1
    int l15 = l & 15, lhi = (l >> 4) & 3;

    // XCD swizzle: 2048 = 8 XCD * 256; each XCD owns one batch image.
    int bid = blockIdx.x;
    int bk = (bid & 7) * 256 + (bid >> 3);
    int b = bk >> 8;
    int u = bk & 255;
    int row = u >> 2;
    int col0 = (u & 3) << 4;

    const __half* xbh = xTh + ((size_t)b << 18);
    const __half* xbl = xTl + ((size_t)b << 18);

    // ---------------- Phase A: stage1 conv, wave w = c-half w ----------------
    {
        f32x4 accA0 = {0.f, 0.f, 0.f, 0.f};
        f32x4 accA1 = {0.f, 0.f, 0.f, 0.f};
        int colp = col0 + l15;
        half8_t Z;
#pragma unroll
        for (int e = 0; e < 8; ++e) Z[e] = (_Float16)0.f;

#pragma unroll
        for (int tr = 0; tr < 3; ++tr) {
            int rsh = row + tr - 1;
            if ((unsigned)rsh >= 64u) continue;     // wave-uniform border skip
#pragma unroll
            for (int tc = 0; tc < 3; ++tc) {
                int tap = tr * 3 + tc;
                int cs = colp + tc - 1;
                bool vcol = (unsigned)cs < 64u;
                size_t poff = (size_t)((rsh << 6) + (vcol ? cs : 0)) * 64 +
                              w * 32 + (lhi << 3);
                half8_t Ah = *(const half8_t*)(xbh + poff);
                half8_t Al = *(const half8_t*)(xbl + poff);
                if (!vcol) { Ah = Z; Al = Z; }
                const __half* wsh = WtSh + tap * 2048 + l15 * 64 + w * 32 + (lhi << 3);
                const __half* wsl = WtSl + tap * 2048 + l15 * 64 + w * 32 + (lhi << 3);
                {
                    half8_t Bh = *(const half8_t*)(wsh);
                    half8_t Bl = *(const half8_t*)(wsl);
                    accA0 = __builtin_amdgcn_mfma_f32_16x16x32_f16(Ah, Bh, accA0, 0, 0, 0);
                    accA0 = __builtin_amdgcn_mfma_f32_16x16x32_f16(Ah, Bl, accA0, 0, 0, 0);
                    accA0 = __builtin_amdgcn_mfma_f32_16x16x32_f16(Al, Bh, accA0, 0, 0, 0);
                }
                {
                    half8_t Bh = *(const half8_t*)(wsh + 1024);
                    half8_t Bl = *(const half8_t*)(wsl + 1024);
                    accA1 = __builtin_amdgcn_mfma_f32_16x16x32_f16(Ah, Bh, accA1, 0, 0, 0);
                    accA1 = __builtin_amdgcn_mfma_f32_16x16x32_f16(Ah, Bl, accA1, 0, 0, 0);
                    accA1 = __builtin_amdgcn_mfma_f32_16x16x32_f16(Al, Bh, accA1, 0, 0, 0);
                }
            }
        }
#pragma unroll
        for (int v4 = 0; v4 < 4; ++v4) {
            Cw[w][(lhi << 2) + v4][l15] = accA0[v4];
            Cw[w][(lhi << 2) + v4][16 + l15] = accA1[v4];
        }
    }
    __syncthreads();

    // ---------------- records: 16 pix x 9 n (144 tasks / 128 threads) ---------
#pragma unroll
    for (int j = 0; j < 2; ++j) {
        int rid = j * 128 + t;
        if (rid < 144) {
            int n = rid >> 4;
            int p = rid & 15;
            float sx = Cw[0][p][n] + Cw[1][p][n];
            float sy = Cw[0][p][9 + n] + Cw[1][p][9 + n];
            float sm = Cw[0][p][18 + n] + Cw[1][p][18 + n];
            int jj = col0 + p;

            float px = ((sx + shift_b[n]) + (float)(n / 3 - 1)) + (float)(row + 1);
            float py = ((sy + shift_b[9 + n]) + (float)(n % 3 - 1)) + (float)(jj + 1);
            float mod = 1.f / (1.f + expf(-(sm + mod_b[n])));

            float fx = floorf(px), fy = floorf(py);
            int ltx = (int)fminf(fmaxf(fx, 0.f), 63.f);
            int lty = (int)fminf(fmaxf(fy, 0.f), 63.f);
            int rbx = (int)fminf(fmaxf(fx + 1.f, 0.f), 63.f);
            int rby = (int)fminf(fmaxf(fy + 1.f, 0.f), 63.f);
            int pxi = (int)fminf(fmaxf(px, 0.f), 63.f);
            int pyi = (int)fminf(fmaxf(py, 0.f), 63.f);

            int g_lt = (1 + ltx - pxi) * (1 + lty - pyi);
            int g_rb = (1 - rbx + pxi) * (1 - rby + pyi);
            int g_lb = (1 + ltx - pxi) * (1 + rby - pyi);
            int g_rt = (1 - rbx + pxi) * (1 - lty + pyi);

            int qxa[4] = {ltx, rbx, ltx, rbx};
            int qya[4] = {lty, rby, rby, lty};
            int gga[4] = {g_lt, g_rb, g_lb, g_rt};
            unsigned w0 = 0, w1 = 0;
#pragma unroll
            for (int jq = 0; jq < 4; ++jq) {
                bool valid = (qxa[jq] >= 1) && (qya[jq] >= 1);
                unsigned idx = valid ? (unsigned)((qxa[jq] - 1) * 64 + (qya[jq] - 1)) : 0u;
                unsigned gc = valid ? (unsigned)gga[jq] : 0u;   // 0..2
                if (jq < 2) w0 |= idx << (12 * jq); else w1 |= idx << (12 * (jq - 2));
                w0 |= gc << (24 + 2 * jq);
            }
            recA[n][p] = make_uint4(w0, w1, __float_as_uint(mod), 0u);
        }
    }
    __syncthreads();

    // ---------------- Phase B: 9 taps, barrier-free, wave = 64 outputs --------
    int obase = w << 6;               // this wave's output base (0 or 64)
    f32x4 acc[4];
#pragma unroll
    for (int g = 0; g < 4; ++g) acc[g] = (f32x4){0.f, 0.f, 0.f, 0.f};

#define LOADG(Gd, rcv)                                                        \
    {                                                                         \
        int id0 = (int)((rcv).x & 0xFFF);                                     \
        int id1 = (int)(((rcv).x >> 12) & 0xFFF);                             \
        int id2 = (int)((rcv).y & 0xFFF);                                     \
        int id3 = (int)(((rcv).y >> 12) & 0xFFF);                             \
        const __half* p0 = xbh + (id0 << 6) + (lhi << 3);                     \
        const __half* p1 = xbh + (id1 << 6) + (lhi << 3);                     \
        const __half* p2 = xbh + (id2 << 6) + (lhi << 3);                     \
        const __half* p3 = xbh + (id3 << 6) + (lhi << 3);                     \
        Gd[0] = *(const uint4*)(p0); Gd[1] = *(const uint4*)(p0 + 32);        \
        Gd[2] = *(const uint4*)(p1); Gd[3] = *(const uint4*)(p1 + 32);        \
        Gd[4] = *(const uint4*)(p2); Gd[5] = *(const uint4*)(p2 + 32);        \
        Gd[6] = *(const uint4*)(p3); Gd[7] = *(const uint4*)(p3 + 32);        \
    }

    uint4 rc = recA[0][l15];
    uint4 G[8];
    LOADG(G, rc);

#pragma unroll
    for (int n = 0; n < 9; ++n) {
        // 1) issue this tap's 8 B-loads first (latency covered by combine)
        const __half* Wn = WtH + n * 8192;
        uint4 Bv[2][4];
#pragma unroll
        for (int ks = 0; ks < 2; ++ks)
#pragma unroll
            for (int g = 0; g < 4; ++g)
                Bv[ks][g] = *(const uint4*)(Wn + ((obase + g * 16 + l15) << 6) +
                                            ks * 32 + (lhi << 3));

        // 2) combine current gathers -> A fragments (G dies here)
        float mod = __uint_as_float(rc.z);
        half8_t Af[2];
#pragma unroll
        for (int ks = 0; ks < 2; ++ks) {
            __half2 a0(0, 0), a1(0, 0), a2(0, 0), a3(0, 0);
#pragma unroll
            for (int j = 0; j < 4; ++j) {
                float wf = (float)((rc.x >> (24 + 2 * j)) & 3) * mod;
                __half2 wh2 = __half2(__float2half_rn(wf), __float2half_rn(wf));
                const __half2* vv = (const __half2*)&G[j * 2 + ks];
                a0 = __hfma2(wh2, vv[0], a0);
                a1 = __hfma2(wh2, vv[1], a1);
                a2 = __hfma2(wh2, vv[2], a2);
                a3 = __hfma2(wh2, vv[3], a3);
            }
            __align__(16) __half2 tmp[4] = {a0, a1, a2, a3};
            Af[ks] = *(half8_t*)tmp;
        }

        // 3) re-issue gathers for next tap into the same registers
        if (n < 8) {
            rc = recA[n + 1][l15];
            LOADG(G, rc);
        }

        // 4) MFMAs (wait only on Bv; gathers stay in flight)
#pragma unroll
        for (int ks = 0; ks < 2; ++ks)
#pragma unroll
            for (int g = 0; g < 4; ++g) {
                half8_t Bf = *(half8_t*)&Bv[ks][g];
                acc[g] = __builtin_amdgcn_mfma_f32_16x16x32_f16(Af[ks], Bf,
                                                                acc[g], 0, 0, 0);
            }
    }
#undef LOADG

    // ---------------- Epilogue: direct float4 stores ----------------
    float* ob = out + ((size_t)b << 19);
    int prow = (row << 6) + col0 + (lhi << 2);
#pragma unroll
    for (int og = 0; og < 4; ++og) {
        int o = obase + og * 16 + l15;
        float* dst = ob + (((size_t)o) << 12) + prow;
        *(float4*)dst = *(float4*)&acc[og];
    }
}

// ---------------------------------------------------------------------------
extern "C" void kernel_launch(void* const* d_in, const int* in_sizes, int n_in,
                              void* d_out, int out_size, void* d_ws, size_t ws_size,
                              hipStream_t stream) {
    const float* x = (const float*)d_in[0];
    const float* shift_w = (const float*)d_in[1];
    const float* shift_b = (const float*)d_in[2];
    const float* mod_w = (const float*)d_in[3];
    const float* mod_b = (const float*)d_in[4];
    const float* conv_w = (const float*)d_in[5];
    float* out = (float*)d_out;

    char* ws = (char*)d_ws;
    __half* xTh = (__half*)ws;                       // 4 MB
    __half* xTl = (__half*)(ws + 4194304);           // 4 MB
    __half* WtH = (__half*)(ws + 8388608);           // 144 KB
    __half* WtSh = (__half*)(ws + 8536064);          // 36 KB
    __half* WtSl = (__half*)(ws + 8572928);          // 36 KB  (total 8.61 MB)

    k_pre<<<dim3(872), dim3(256), 0, stream>>>(x, conv_w, shift_w, mod_w,
                                               xTh, xTl, WtH, WtSh, WtSl);
    k_dual<<<dim3(2048), dim3(128), 0, stream>>>(xTh, xTl, WtH, WtSh, WtSl,
                                                 shift_b, mod_b, out);
}

// Round 11
// 39.157 us; speedup vs baseline: 2.5408x; 2.5408x over previous
//
#include <hip/hip_runtime.h>
#include <hip/hip_fp16.h>
#include <math.h>

// B=8, C=64, H=W=64, O=128, K=3, N=9, stride=1, pad=1
// ws layout (12.8 MB):
//   xTh   @ 0         : fp16 hi(x)  [8][4096 pix][64 c] = 4,194,304 B
//   xTl   @ 4194304   : fp16 lo(x)  [8][4096 pix][64 c] = 4,194,304 B
//   xCb   @ 8388608   : fp16 (x[p]+2x[p+1]) [8][4096][64] = 4,194,304 B
//   WtF   @ 12582912  : fp16 main W in MFMA-fragment order  = 147,456 B
//   WtSFh @ 12730368  : fp16 stage1 W hi, fragment order    =  36,864 B
//   WtSFl @ 12767232  : fp16 stage1 W lo, fragment order    =  36,864 B

typedef _Float16 half8_t __attribute__((ext_vector_type(8)));
typedef float f32x4 __attribute__((ext_vector_type(4)));

// ---------------------------------------------------------------------------
// k_pre: blocks 0..511: x -> xTh/xTl (split fp16, [pix][c]) and xCb
//        blocks 512..871: W -> fragment-order tables
// Fragment order: a wave load at (ks,g,...) reads lane l's 8 halves
// contiguously -> 1KB fully-coalesced loads in the main kernel.
// ---------------------------------------------------------------------------
__global__ __launch_bounds__(256) void k_pre(const float* __restrict__ x,
                                             const float* __restrict__ cw,
                                             const float* __restrict__ shift_w,
                                             const float* __restrict__ mod_w,
                                             __half* __restrict__ xTh,
                                             __half* __restrict__ xTl,
                                             __half* __restrict__ xCb,
                                             __half* __restrict__ WtF,
                                             __half* __restrict__ WtSFh,
                                             __half* __restrict__ WtSFl) {
    __shared__ float tile[64][65];
    int bid = blockIdx.x;
    int t = threadIdx.x;
    if (bid < 512) {
        int b = bid >> 6, pt = bid & 63;            // pt = image row
        int lane = t & 63, cq = t >> 6;
        const float* xb = x + ((size_t)b << 18);
#pragma unroll
        for (int r = 0; r < 16; ++r) {
            int c = cq * 16 + r;
            tile[c][lane] = xb[((size_t)c << 12) + pt * 64 + lane];
        }
        __syncthreads();
        int p = t >> 2, qc = t & 3;
        __align__(16) _Float16 hh[16];
        __align__(16) _Float16 ll[16];
        __align__(16) _Float16 cb[16];
#pragma unroll
        for (int k = 0; k < 16; ++k) {
            float v0 = tile[qc * 16 + k][p];
            float v1 = (p < 63) ? tile[qc * 16 + k][p + 1] : 0.f;  // col63 unused
            _Float16 h = (_Float16)v0;
            hh[k] = h;
            ll[k] = (_Float16)(v0 - (float)h);
            cb[k] = (_Float16)(v0 + 2.f * v1);      // degenerate bilinear, 1 rounding
        }
        size_t off = ((size_t)b << 18) + (size_t)(pt * 64 + p) * 64 + qc * 16;
        ((uint4*)(xTh + off))[0] = ((uint4*)hh)[0];
        ((uint4*)(xTh + off))[1] = ((uint4*)hh)[1];
        ((uint4*)(xTl + off))[0] = ((uint4*)ll)[0];
        ((uint4*)(xTl + off))[1] = ((uint4*)ll)[1];
        ((uint4*)(xCb + off))[0] = ((uint4*)cb)[0];
        ((uint4*)(xCb + off))[1] = ((uint4*)cb)[1];
    } else {
        int u = (bid - 512) * 256 + t;
        if (u < 73728) {
            // WtF[((n*2+w)*4+g)*2+ks][lane][e] = W[o=w*64+g*16+(l&15)][c=ks*32+(l>>4)*8+e]
            int e = u & 7, l = (u >> 3) & 63, ks = (u >> 9) & 1;
            int g = (u >> 10) & 3, w = (u >> 12) & 1, n = u >> 13;
            int o = w * 64 + g * 16 + (l & 15);
            int c = ks * 32 + (l >> 4) * 8 + e;
            WtF[u] = __float2half_rn(cw[(o * 64 + c) * 9 + n]);
        } else {
            int q = u - 73728;
            if (q < 18432) {
                // WtSF[(tap*2+chf)*2+nf][lane][e] = Ws[ch=nf*16+(l&15)][c=chf*32+(l>>4)*8+e]
                int e = q & 7, l = (q >> 3) & 63, nf = (q >> 9) & 1;
                int chf = (q >> 10) & 1, tap = q >> 11;
                int ch = nf * 16 + (l & 15);
                int c = chf * 32 + (l >> 4) * 8 + e;
                float wv = 0.f;
                if (ch < 18) wv = shift_w[(ch * 64 + c) * 9 + tap];
                else if (ch < 27) wv = mod_w[((ch - 18) * 64 + c) * 9 + tap];
                _Float16 h = (_Float16)wv;
                _Float16 lo = (_Float16)(wv - (float)h);
                WtSFh[q] = *(__half*)&h;
                WtSFl[q] = *(__half*)&lo;
            }
        }
    }
}

// ---------------------------------------------------------------------------
// k_fused: block = 32 pixels (half image row) x 128 outputs, 4 waves.
//   grid 1024, LDS 39.9KB -> 4 blocks/CU (16 waves/CU).
//   Stage: halo tile (3 rows x 34 cols, h+l) coalesced into LDS, XOR-swizzled.
//   Phase A: stage1 conv via split-fp16 MFMA; A from LDS (conflict-free),
//            B = 1KB coalesced fragment-order loads. Branchless (zeros staged).
//   Records: exact reference math + 'simple' flag (interior degenerate case).
//   Phase B: per tap: 1 coalesced xCb gather per (pix,cg-chunk) when simple
//            (rare 4-slot fallback), Bv = 1KB coalesced loads; slab dbuf,
//            1 barrier/tap; MFMA 8/wave/tap.
// ---------------------------------------------------------------------------
__global__ __launch_bounds__(256, 4) void k_fused(
    const __half* __restrict__ xTh, const __half* __restrict__ xTl,
    const __half* __restrict__ xCb, const __half* __restrict__ WtF,
    const __half* __restrict__ WtSFh, const __half* __restrict__ WtSFl,
    const float* __restrict__ shift_b, const float* __restrict__ mod_b,
    float* __restrict__ out) {
    // arena: stage: tileH @0 (13056), tileL @13056 (13056)
    //        phase B: slab0 @0 (4096), slab1 @4096 (4096); epilogue Ep @8192 (4224)
    __shared__ __align__(16) unsigned char arena[26112];
    __shared__ float Cw[2][2][16][36];   // [wh][wp][pix16][ch(36)]
    __shared__ uint4 recA[9][32];

    int t = threadIdx.x;
    int l = t & 63;
    int w = t >> 6;
    int l15 = l & 15, lhi = l >> 4;

    // XCD swizzle: 1024 = 8 XCD x 128; each XCD gets one batch image.
    int bid = blockIdx.x;
    int bk = (bid & 7) * 128 + (bid >> 3);
    int b = bk >> 7;
    int u = bk & 127;
    int row = u >> 1;
    int hf = u & 1;
    int col0 = hf * 32;

    const __half* xbh = xTh + ((size_t)b << 18);
    const __half* xbl = xTl + ((size_t)b << 18);
    const __half* xbc = xCb + ((size_t)b << 18);

    // ---------------- stage halo tile (coalesced, swizzled, zero-padded) ------
#pragma unroll
    for (int rr = 0; rr < 7; ++rr) {
        int d = rr * 256 + t;
        if (d < 1632) {
            int bufl = d >= 816 ? 1 : 0;
            int dd = d - bufl * 816;
            int s = dd >> 3, cb8 = dd & 7;       // slot s (102), 16B chunk cb8
            int r = s / 34, j = s - r * 34;
            int grow = row + r - 1;
            int gcol = col0 - 1 + j;
            uint4 v = make_uint4(0u, 0u, 0u, 0u);
            if ((unsigned)grow < 64u && (unsigned)gcol < 64u) {
                const __half* src = (bufl ? xbl : xbh) +
                                    ((size_t)((grow << 6) + gcol) << 6) + (cb8 << 3);
                v = *(const uint4*)src;
            }
            int dst = bufl * 13056 + s * 128 + ((cb8 << 4) ^ ((s & 7) << 4));
            *(uint4*)&arena[dst] = v;
        }
    }
    __syncthreads();

    // ---------------- Phase A: wave (wp = w>>1, wh = w&1) ----------------
    {
        int wp = w >> 1, wh = w & 1;
        f32x4 accA[2];
        accA[0] = (f32x4){0.f, 0.f, 0.f, 0.f};
        accA[1] = (f32x4){0.f, 0.f, 0.f, 0.f};
#pragma unroll
        for (int tr = 0; tr < 3; ++tr)
#pragma unroll
            for (int tc = 0; tc < 3; ++tc) {
                int tap = tr * 3 + tc;
                int j = wp * 16 + l15 + tc;      // tile col 0..33
                int s = tr * 34 + j;
                int cbyte = (wh << 6) + (lhi << 4);
                int addr = s * 128 + (cbyte ^ ((s & 7) << 4));
                half8_t Ah = *(const half8_t*)&arena[addr];
                half8_t Al = *(const half8_t*)&arena[13056 + addr];
#pragma unroll
                for (int nf = 0; nf < 2; ++nf) {
                    int fo = ((((tap << 1) + wh) << 1) + nf) << 9;
                    half8_t Bh = *(const half8_t*)(WtSFh + fo + (l << 3));
                    half8_t Bl = *(const half8_t*)(WtSFl + fo + (l << 3));
                    accA[nf] = __builtin_amdgcn_mfma_f32_16x16x32_f16(Ah, Bh, accA[nf], 0, 0, 0);
                    accA[nf] = __builtin_amdgcn_mfma_f32_16x16x32_f16(Ah, Bl, accA[nf], 0, 0, 0);
                    accA[nf] = __builtin_amdgcn_mfma_f32_16x16x32_f16(Al, Bh, accA[nf], 0, 0, 0);
                }
            }
#pragma unroll
        for (int nf = 0; nf < 2; ++nf)
#pragma unroll
            for (int v4 = 0; v4 < 4; ++v4)
                Cw[wh][wp][(lhi << 2) + v4][nf * 16 + l15] = accA[nf][v4];
    }
    __syncthreads();

    // ---------------- records: 32 pix x 9 n (+ simple flag) ----------------
#pragma unroll
    for (int jj0 = 0; jj0 < 2; ++jj0) {
        int rid = jj0 * 256 + t;
        if (rid < 288) {
            int p = rid & 31;
            int n = rid >> 5;
            int wp = p >> 4, pp = p & 15;
            float sx = Cw[0][wp][pp][n] + Cw[1][wp][pp][n];
            float sy = Cw[0][wp][pp][9 + n] + Cw[1][wp][pp][9 + n];
            float sm = Cw[0][wp][pp][18 + n] + Cw[1][wp][pp][18 + n];
            int jc = col0 + p;

            float px = ((sx + shift_b[n]) + (float)(n / 3 - 1)) + (float)(row + 1);
            float py = ((sy + shift_b[9 + n]) + (float)(n % 3 - 1)) + (float)(jc + 1);
            float mod = 1.f / (1.f + expf(-(sm + mod_b[n])));

            float fx = floorf(px), fy = floorf(py);
            int ltx = (int)fminf(fmaxf(fx, 0.f), 63.f);
            int lty = (int)fminf(fmaxf(fy, 0.f), 63.f);
            int rbx = (int)fminf(fmaxf(fx + 1.f, 0.f), 63.f);
            int rby = (int)fminf(fmaxf(fy + 1.f, 0.f), 63.f);
            int pxi = (int)fminf(fmaxf(px, 0.f), 63.f);
            int pyi = (int)fminf(fmaxf(py, 0.f), 63.f);

            int g_lt = (1 + ltx - pxi) * (1 + lty - pyi);
            int g_rb = (1 - rbx + pxi) * (1 - rby + pyi);
            int g_lb = (1 + ltx - pxi) * (1 + rby - pyi);
            int g_rt = (1 - rbx + pxi) * (1 - lty + pyi);

            // simple <=> weights {1,0,2,0} with both slots valid; then
            // x_off = x[a] + 2x[a+1] = xCb[a], a = (ltx-1)*64 + (lty-1)
            bool simple = (ltx == pxi) && (lty == pyi) && (rbx == pxi + 1) &&
                          (rby == pyi + 1) && (ltx >= 1) && (lty >= 1);

            int qxa[4] = {ltx, rbx, ltx, rbx};
            int qya[4] = {lty, rby, rby, lty};
            int gga[4] = {g_lt, g_rb, g_lb, g_rt};
            unsigned w0 = 0, w1 = 0;
#pragma unroll
            for (int jq = 0; jq < 4; ++jq) {
                bool valid = (qxa[jq] >= 1) && (qya[jq] >= 1);
                unsigned idx = valid ? (unsigned)((qxa[jq] - 1) * 64 + (qya[jq] - 1)) : 0u;
                unsigned gc = valid ? (unsigned)gga[jq] : 0u;   // 0..2
                if (jq < 2) w0 |= idx << (12 * jq); else w1 |= idx << (12 * (jq - 2));
                w0 |= gc << (24 + 2 * jq);
            }
            if (simple) w1 |= 0x80000000u;
            recA[n][p] = make_uint4(w0, w1, __float_as_uint(mod), 0u);
        }
    }
    __syncthreads();

    // ---------------- Phase B: 9 taps, slab dbuf, 1 barrier/tap ----------------
    int wm = w >> 1, wn = w & 1;
    int mA = t >> 3, cg = t & 7;        // A-build task: pixel mA, c-chunk cg

    f32x4 acc[4];
#pragma unroll
    for (int g = 0; g < 4; ++g) acc[g] = (f32x4){0.f, 0.f, 0.f, 0.f};

    for (int n = 0; n < 9; ++n) {
        // B fragments: 1KB fully-coalesced loads (L1/L2-hot, same for all blocks)
        uint4 Bv[2][4];
#pragma unroll
        for (int ks = 0; ks < 2; ++ks)
#pragma unroll
            for (int g = 0; g < 4; ++g) {
                int fo = ((((((n << 1) + wn) << 2) + g) << 1) + ks) << 9;
                Bv[ks][g] = *(const uint4*)(WtF + fo + (l << 3));
            }

        // A build: simple = 1 coalesced xCb line per pixel; else 4-slot fallback
        uint4 rc = recA[n][mA];
        float mod = __uint_as_float(rc.z);
        __align__(16) __half2 a2[4];
        if (rc.y >> 31) {
            int idx = (int)(rc.x & 0xFFF);
            uint4 v = *(const uint4*)(xbc + (idx << 6) + (cg << 3));
            __half mh = __float2half_rn(mod);
            __half2 mm(mh, mh);
            const __half2* vv = (const __half2*)&v;
            a2[0] = __hmul2(mm, vv[0]);
            a2[1] = __hmul2(mm, vv[1]);
            a2[2] = __hmul2(mm, vv[2]);
            a2[3] = __hmul2(mm, vv[3]);
        } else {
            a2[0] = __half2(0, 0); a2[1] = __half2(0, 0);
            a2[2] = __half2(0, 0); a2[3] = __half2(0, 0);
#pragma unroll
            for (int jq = 0; jq < 4; ++jq) {
                int id = (int)((jq < 2 ? (rc.x >> (12 * jq))
                                       : (rc.y >> (12 * (jq - 2)))) & 0xFFF);
                float wf = (float)((rc.x >> (24 + 2 * jq)) & 3) * mod;
                __half2 wh2 = __half2(__float2half_rn(wf), __float2half_rn(wf));
                uint4 v = *(const uint4*)(xbh + (id << 6) + (cg << 3));
                const __half2* vv = (const __half2*)&v;
                a2[0] = __hfma2(wh2, vv[0], a2[0]);
                a2[1] = __hfma2(wh2, vv[1], a2[1]);
                a2[2] = __hfma2(wh2, vv[2], a2[2]);
                a2[3] = __hfma2(wh2, vv[3], a2[3]);
            }
        }
        *(uint4*)&arena[((n & 1) << 12) | (mA << 7) | ((cg ^ (mA & 7)) << 4)] =
            *(uint4*)a2;
        __syncthreads();    // slab[n&1] complete (double-buffer -> 1 bar/tap)

        // MFMA: A rows wm*16 + l15
#pragma unroll
        for (int ks = 0; ks < 2; ++ks) {
            int rowa = wm * 16 + l15;
            int gr = (ks * 4 + lhi) ^ (rowa & 7);
            half8_t Af = *(const half8_t*)&arena[((n & 1) << 12) | (rowa << 7) | (gr << 4)];
#pragma unroll
            for (int g = 0; g < 4; ++g) {
                half8_t Bf = *(half8_t*)&Bv[ks][g];
                acc[g] = __builtin_amdgcn_mfma_f32_16x16x32_f16(Af, Bf, acc[g], 0, 0, 0);
            }
        }
    }

    // ---------------- Epilogue: 4 rounds of 32 o-rows (R7-verbatim) -----------
    float* Ep = (float*)(arena + 8192);   // [32 o][33 m]
    float* ob = out + ((size_t)b << 19);
    int prow = (row << 6) + col0;
#pragma unroll
    for (int r = 0; r < 4; ++r) {
        if (wn == (r >> 1)) {
#pragma unroll
            for (int gg = 0; gg < 2; ++gg) {
                int g = (r & 1) * 2 + gg;
                int o_loc = gg * 16 + l15;
#pragma unroll
                for (int v4 = 0; v4 < 4; ++v4)
                    Ep[o_loc * 33 + wm * 16 + (lhi << 2) + v4] = acc[g][v4];
            }
        }
        __syncthreads();
        {
            int o_loc = t >> 3;
            int mseg = t & 7;
            float4 fa;
            fa.x = Ep[o_loc * 33 + mseg * 4 + 0];
            fa.y = Ep[o_loc * 33 + mseg * 4 + 1];
            fa.z = Ep[o_loc * 33 + mseg * 4 + 2];
            fa.w = Ep[o_loc * 33 + mseg * 4 + 3];
            float* dst = ob + (((size_t)(r * 32 + o_loc)) << 12) + prow + mseg * 4;
            *(float4*)dst = fa;
        }
        __syncthreads();
    }
}

// ---------------------------------------------------------------------------
extern "C" void kernel_launch(void* const* d_in, const int* in_sizes, int n_in,
                              void* d_out, int out_size, void* d_ws, size_t ws_size,
                              hipStream_t stream) {
    const float* x = (const float*)d_in[0];
    const float* shift_w = (const float*)d_in[1];
    const float* shift_b = (const float*)d_in[2];
    const float* mod_w = (const float*)d_in[3];
    const float* mod_b = (const float*)d_in[4];
    const float* conv_w = (const float*)d_in[5];
    float* out = (float*)d_out;

    char* ws = (char*)d_ws;
    __half* xTh = (__half*)ws;                         // 4 MB
    __half* xTl = (__half*)(ws + 4194304);             // 4 MB
    __half* xCb = (__half*)(ws + 8388608);             // 4 MB
    __half* WtF = (__half*)(ws + 12582912);            // 144 KB
    __half* WtSFh = (__half*)(ws + 12730368);          // 36 KB
    __half* WtSFl = (__half*)(ws + 12767232);          // 36 KB  (total 12.8 MB)

    k_pre<<<dim3(872), dim3(256), 0, stream>>>(x, conv_w, shift_w, mod_w,
                                               xTh, xTl, xCb, WtF, WtSFh, WtSFl);
    k_fused<<<dim3(1024), dim3(256), 0, stream>>>(xTh, xTl, xCb, WtF, WtSFh,
                                                  WtSFl, shift_b, mod_b, out);
}

// Round 13
// 36.449 us; speedup vs baseline: 2.7296x; 1.0743x over previous
//
#include <hip/hip_runtime.h>
#include <hip/hip_fp16.h>
#include <math.h>

// B=8, C=64, H=W=64, O=128, K=3, N=9, stride=1, pad=1
// ws layout (12.8 MB):
//   xTh   @ 0         : fp16 hi(x)  [8][4096 pix][64 c] = 4,194,304 B
//   xTl   @ 4194304   : fp16 lo(x)  [8][4096 pix][64 c] = 4,194,304 B
//   xCb   @ 8388608   : fp16 (x[p]+2x[p+1]) [8][4096][64] = 4,194,304 B
//   WtF   @ 12582912  : fp16 main W in MFMA-fragment order  = 147,456 B
//   WtSFh @ 12730368  : fp16 stage1 W hi, fragment order    =  36,864 B
//   WtSFl @ 12767232  : fp16 stage1 W lo, fragment order    =  36,864 B

typedef _Float16 half8_t __attribute__((ext_vector_type(8)));
typedef float f32x4 __attribute__((ext_vector_type(4)));

// ---------------------------------------------------------------------------
// k_pre (R11-verbatim): x -> xTh/xTl/xCb ; W -> fragment-order tables
// ---------------------------------------------------------------------------
__global__ __launch_bounds__(256) void k_pre(const float* __restrict__ x,
                                             const float* __restrict__ cw,
                                             const float* __restrict__ shift_w,
                                             const float* __restrict__ mod_w,
                                             __half* __restrict__ xTh,
                                             __half* __restrict__ xTl,
                                             __half* __restrict__ xCb,
                                             __half* __restrict__ WtF,
                                             __half* __restrict__ WtSFh,
                                             __half* __restrict__ WtSFl) {
    __shared__ float tile[64][65];
    int bid = blockIdx.x;
    int t = threadIdx.x;
    if (bid < 512) {
        int b = bid >> 6, pt = bid & 63;            // pt = image row
        int lane = t & 63, cq = t >> 6;
        const float* xb = x + ((size_t)b << 18);
#pragma unroll
        for (int r = 0; r < 16; ++r) {
            int c = cq * 16 + r;
            tile[c][lane] = xb[((size_t)c << 12) + pt * 64 + lane];
        }
        __syncthreads();
        int p = t >> 2, qc = t & 3;
        __align__(16) _Float16 hh[16];
        __align__(16) _Float16 ll[16];
        __align__(16) _Float16 cb[16];
#pragma unroll
        for (int k = 0; k < 16; ++k) {
            float v0 = tile[qc * 16 + k][p];
            float v1 = (p < 63) ? tile[qc * 16 + k][p + 1] : 0.f;  // col63 unused
            _Float16 h = (_Float16)v0;
            hh[k] = h;
            ll[k] = (_Float16)(v0 - (float)h);
            cb[k] = (_Float16)(v0 + 2.f * v1);      // degenerate bilinear
        }
        size_t off = ((size_t)b << 18) + (size_t)(pt * 64 + p) * 64 + qc * 16;
        ((uint4*)(xTh + off))[0] = ((uint4*)hh)[0];
        ((uint4*)(xTh + off))[1] = ((uint4*)hh)[1];
        ((uint4*)(xTl + off))[0] = ((uint4*)ll)[0];
        ((uint4*)(xTl + off))[1] = ((uint4*)ll)[1];
        ((uint4*)(xCb + off))[0] = ((uint4*)cb)[0];
        ((uint4*)(xCb + off))[1] = ((uint4*)cb)[1];
    } else {
        int u = (bid - 512) * 256 + t;
        if (u < 73728) {
            int e = u & 7, l = (u >> 3) & 63, ks = (u >> 9) & 1;
            int g = (u >> 10) & 3, w = (u >> 12) & 1, n = u >> 13;
            int o = w * 64 + g * 16 + (l & 15);
            int c = ks * 32 + (l >> 4) * 8 + e;
            WtF[u] = __float2half_rn(cw[(o * 64 + c) * 9 + n]);
        } else {
            int q = u - 73728;
            if (q < 18432) {
                int e = q & 7, l = (q >> 3) & 63, nf = (q >> 9) & 1;
                int chf = (q >> 10) & 1, tap = q >> 11;
                int ch = nf * 16 + (l & 15);
                int c = chf * 32 + (l >> 4) * 8 + e;
                float wv = 0.f;
                if (ch < 18) wv = shift_w[(ch * 64 + c) * 9 + tap];
                else if (ch < 27) wv = mod_w[((ch - 18) * 64 + c) * 9 + tap];
                _Float16 h = (_Float16)wv;
                _Float16 lo = (_Float16)(wv - (float)h);
                WtSFh[q] = *(__half*)&h;
                WtSFl[q] = *(__half*)&lo;
            }
        }
    }
}

// ---------------------------------------------------------------------------
// k_fused: block = 64 pixels (one image row) x 128 outputs, 8 waves (512 thr).
//   grid 512, LDS 76.5 KB -> 2 blocks/CU (16 waves/CU, same as R11).
//   vs R11: 2x pixels/block (halves W+stage traffic per pixel), main-GEMM W
//   staged through LDS per tap (4x less W L1 traffic), one-shot epilogue.
//   R12 bug fixed: epilogue pitch 33 -> 65 (64 pixels per row; 33 aliased).
// ---------------------------------------------------------------------------
__global__ __launch_bounds__(512, 2) void k_fused(
    const __half* __restrict__ xTh, const __half* __restrict__ xTl,
    const __half* __restrict__ xCb, const __half* __restrict__ WtF,
    const __half* __restrict__ WtSFh, const __half* __restrict__ WtSFl,
    const float* __restrict__ shift_b, const float* __restrict__ mod_b,
    float* __restrict__ out) {
    // arena: stage: tileH @0 (25344), tileL @25344 (25344)
    //        phase B: A slabs @0,@8192 (8KB each); W slabs @16384,@32768 (16KB each)
    //        epilogue: Ep f32[128][65] @0 (33280), after post-MFMA barrier
    __shared__ __align__(16) unsigned char arena[50688];
    __shared__ float Cw[2][4][16][36];   // [wh][wp][pix16][ch(36)]
    __shared__ uint4 recA[9][64];

    int t = threadIdx.x;
    int l = t & 63;
    int w = t >> 6;                       // 8 waves
    int l15 = l & 15, lhi = l >> 4;

    // XCD swizzle: 512 = 8 XCD x 64; each XCD gets one batch image.
    int bid = blockIdx.x;
    int bk = (bid & 7) * 64 + (bid >> 3);
    int b = bk >> 6;
    int row = bk & 63;

    const __half* xbh = xTh + ((size_t)b << 18);
    const __half* xbl = xTl + ((size_t)b << 18);
    const __half* xbc = xCb + ((size_t)b << 18);

    // ---------------- stage halo tile: 3 rows x 66 cols, h+l ----------------
#pragma unroll
    for (int rr = 0; rr < 7; ++rr) {
        int d = rr * 512 + t;
        if (d < 3168) {
            int bufl = d >= 1584 ? 1 : 0;
            int dd = d - bufl * 1584;
            int s = dd >> 3, cb8 = dd & 7;   // slot s (198), 16B chunk cb8
            int r = s / 66, j = s - r * 66;
            int grow = row + r - 1;
            int gcol = j - 1;
            uint4 v = make_uint4(0u, 0u, 0u, 0u);
            if ((unsigned)grow < 64u && (unsigned)gcol < 64u) {
                const __half* src = (bufl ? xbl : xbh) +
                                    ((size_t)((grow << 6) + gcol) << 6) + (cb8 << 3);
                v = *(const uint4*)src;
            }
            int dst = bufl * 25344 + s * 128 + ((cb8 << 4) ^ ((s & 7) << 4));
            *(uint4*)&arena[dst] = v;
        }
    }
    __syncthreads();

    // ---------------- Phase A: wave (wp = w>>1 in 0..3, wh = w&1) -------------
    {
        int wp = w >> 1, wh = w & 1;
        f32x4 accA[2];
        accA[0] = (f32x4){0.f, 0.f, 0.f, 0.f};
        accA[1] = (f32x4){0.f, 0.f, 0.f, 0.f};
#pragma unroll
        for (int tr = 0; tr < 3; ++tr)
#pragma unroll
            for (int tc = 0; tc < 3; ++tc) {
                int tap = tr * 3 + tc;
                int j = wp * 16 + l15 + tc;      // tile col 0..65
                int s = tr * 66 + j;
                int cbyte = (wh << 6) + (lhi << 4);
                int addr = s * 128 + (cbyte ^ ((s & 7) << 4));
                half8_t Ah = *(const half8_t*)&arena[addr];
                half8_t Al = *(const half8_t*)&arena[25344 + addr];
#pragma unroll
                for (int nf = 0; nf < 2; ++nf) {
                    int fo = ((((tap << 1) + wh) << 1) + nf) << 9;
                    half8_t Bh = *(const half8_t*)(WtSFh + fo + (l << 3));
                    half8_t Bl = *(const half8_t*)(WtSFl + fo + (l << 3));
                    accA[nf] = __builtin_amdgcn_mfma_f32_16x16x32_f16(Ah, Bh, accA[nf], 0, 0, 0);
                    accA[nf] = __builtin_amdgcn_mfma_f32_16x16x32_f16(Ah, Bl, accA[nf], 0, 0, 0);
                    accA[nf] = __builtin_amdgcn_mfma_f32_16x16x32_f16(Al, Bh, accA[nf], 0, 0, 0);
                }
            }
#pragma unroll
        for (int nf = 0; nf < 2; ++nf)
#pragma unroll
            for (int v4 = 0; v4 < 4; ++v4)
                Cw[wh][wp][(lhi << 2) + v4][nf * 16 + l15] = accA[nf][v4];
    }
    __syncthreads();

    // ---------------- records: 64 pix x 9 n (+ simple flag) ----------------
#pragma unroll
    for (int jj0 = 0; jj0 < 2; ++jj0) {
        int rid = jj0 * 512 + t;
        if (rid < 576) {
            int p = rid & 63;
            int n = rid >> 6;
            int wp = p >> 4, pp = p & 15;
            float sx = Cw[0][wp][pp][n] + Cw[1][wp][pp][n];
            float sy = Cw[0][wp][pp][9 + n] + Cw[1][wp][pp][9 + n];
            float sm = Cw[0][wp][pp][18 + n] + Cw[1][wp][pp][18 + n];

            float px = ((sx + shift_b[n]) + (float)(n / 3 - 1)) + (float)(row + 1);
            float py = ((sy + shift_b[9 + n]) + (float)(n % 3 - 1)) + (float)(p + 1);
            float mod = 1.f / (1.f + expf(-(sm + mod_b[n])));

            float fx = floorf(px), fy = floorf(py);
            int ltx = (int)fminf(fmaxf(fx, 0.f), 63.f);
            int lty = (int)fminf(fmaxf(fy, 0.f), 63.f);
            int rbx = (int)fminf(fmaxf(fx + 1.f, 0.f), 63.f);
            int rby = (int)fminf(fmaxf(fy + 1.f, 0.f), 63.f);
            int pxi = (int)fminf(fmaxf(px, 0.f), 63.f);
            int pyi = (int)fminf(fmaxf(py, 0.f), 63.f);

            int g_lt = (1 + ltx - pxi) * (1 + lty - pyi);
            int g_rb = (1 - rbx + pxi) * (1 - rby + pyi);
            int g_lb = (1 + ltx - pxi) * (1 + rby - pyi);
            int g_rt = (1 - rbx + pxi) * (1 - lty + pyi);

            bool simple = (ltx == pxi) && (lty == pyi) && (rbx == pxi + 1) &&
                          (rby == pyi + 1) && (ltx >= 1) && (lty >= 1);

            int qxa[4] = {ltx, rbx, ltx, rbx};
            int qya[4] = {lty, rby, rby, lty};
            int gga[4] = {g_lt, g_rb, g_lb, g_rt};
            unsigned w0 = 0, w1 = 0;
#pragma unroll
            for (int jq = 0; jq < 4; ++jq) {
                bool valid = (qxa[jq] >= 1) && (qya[jq] >= 1);
                unsigned idx = valid ? (unsigned)((qxa[jq] - 1) * 64 + (qya[jq] - 1)) : 0u;
                unsigned gc = valid ? (unsigned)gga[jq] : 0u;   // 0..2
                if (jq < 2) w0 |= idx << (12 * jq); else w1 |= idx << (12 * (jq - 2));
                w0 |= gc << (24 + 2 * jq);
            }
            if (simple) w1 |= 0x80000000u;
            recA[n][p] = make_uint4(w0, w1, __float_as_uint(mod), 0u);
        }
    }
    __syncthreads();

    // ---------------- Phase B: 9 taps, A+W slabs dbuf, 1 barrier/tap ----------
    int wm = w >> 1, wn = w & 1;        // wm 0..3 (pixel 16-group), wn 0..1 (o-half)
    int mA = t >> 3, cg = t & 7;        // A-build task: pixel mA (0..63), c-chunk cg

    f32x4 acc[4];
#pragma unroll
    for (int g = 0; g < 4; ++g) acc[g] = (f32x4){0.f, 0.f, 0.f, 0.f};

    for (int n = 0; n < 9; ++n) {
        int sl = n & 1;
        // W stage: 16 KB fragment-order slab, coalesced (2 uint4 per thread)
        {
            const uint4* wsrc = (const uint4*)(WtF + n * 8192);
            uint4* wdst = (uint4*)&arena[16384 + (sl << 14)];
            wdst[t] = wsrc[t];
            wdst[512 + t] = wsrc[512 + t];
        }

        // A build: simple = 1 coalesced xCb line; else 4-slot fallback
        {
            uint4 rc = recA[n][mA];
            float mod = __uint_as_float(rc.z);
            __align__(16) __half2 a2[4];
            if (rc.y >> 31) {
                int idx = (int)(rc.x & 0xFFF);
                uint4 v = *(const uint4*)(xbc + (idx << 6) + (cg << 3));
                __half mh = __float2half_rn(mod);
                __half2 mm(mh, mh);
                const __half2* vv = (const __half2*)&v;
                a2[0] = __hmul2(mm, vv[0]);
                a2[1] = __hmul2(mm, vv[1]);
                a2[2] = __hmul2(mm, vv[2]);
                a2[3] = __hmul2(mm, vv[3]);
            } else {
                a2[0] = __half2(0, 0); a2[1] = __half2(0, 0);
                a2[2] = __half2(0, 0); a2[3] = __half2(0, 0);
#pragma unroll
                for (int jq = 0; jq < 4; ++jq) {
                    int id = (int)((jq < 2 ? (rc.x >> (12 * jq))
                                           : (rc.y >> (12 * (jq - 2)))) & 0xFFF);
                    float wf = (float)((rc.x >> (24 + 2 * jq)) & 3) * mod;
                    __half2 wh2 = __half2(__float2half_rn(wf), __float2half_rn(wf));
                    uint4 v = *(const uint4*)(xbh + (id << 6) + (cg << 3));
                    const __half2* vv = (const __half2*)&v;
                    a2[0] = __hfma2(wh2, vv[0], a2[0]);
                    a2[1] = __hfma2(wh2, vv[1], a2[1]);
                    a2[2] = __hfma2(wh2, vv[2], a2[2]);
                    a2[3] = __hfma2(wh2, vv[3], a2[3]);
                }
            }
            *(uint4*)&arena[(sl << 13) | (mA << 7) | ((cg ^ (mA & 7)) << 4)] =
                *(uint4*)a2;
        }
        __syncthreads();    // A+W slabs complete (dbuf -> 1 barrier/tap)

        // MFMA: A rows wm*16 + l15; W fragments from LDS slab
        const unsigned char* wsl = &arena[16384 + (sl << 14)];
#pragma unroll
        for (int ks = 0; ks < 2; ++ks) {
            int rowa = wm * 16 + l15;
            int gr = (ks * 4 + lhi) ^ (rowa & 7);
            half8_t Af = *(const half8_t*)&arena[(sl << 13) | (rowa << 7) | (gr << 4)];
#pragma unroll
            for (int g = 0; g < 4; ++g) {
                half8_t Bf = *(const half8_t*)&wsl[((((wn << 2) + g) << 1) + ks) * 1024 +
                                                   (l << 4)];
                acc[g] = __builtin_amdgcn_mfma_f32_16x16x32_f16(Af, Bf, acc[g], 0, 0, 0);
            }
        }
    }

    // ---------------- Epilogue: one-shot Ep f32[128][65] ----------------
    __syncthreads();                     // all MFMA done; slabs reusable as Ep
    float* Ep = (float*)arena;
#pragma unroll
    for (int g = 0; g < 4; ++g) {
        int o_loc = (wn << 6) + (g << 4) + l15;
#pragma unroll
        for (int v4 = 0; v4 < 4; ++v4)
            Ep[o_loc * 65 + (wm << 4) + (lhi << 2) + v4] = acc[g][v4];
    }
    __syncthreads();
    {
        float* ob = out + ((size_t)b << 19);
        int prow = row << 6;
#pragma unroll
        for (int r = 0; r < 4; ++r) {
            int o_loc = (r << 5) + (t >> 4);   // 0..127
            int mseg = t & 15;                 // 0..15 -> 64 pix
            float4 fa;
            fa.x = Ep[o_loc * 65 + mseg * 4 + 0];
            fa.y = Ep[o_loc * 65 + mseg * 4 + 1];
            fa.z = Ep[o_loc * 65 + mseg * 4 + 2];
            fa.w = Ep[o_loc * 65 + mseg * 4 + 3];
            float* dst = ob + (((size_t)o_loc) << 12) + prow + mseg * 4;
            *(float4*)dst = fa;
        }
    }
}

// ---------------------------------------------------------------------------
extern "C" void kernel_launch(void* const* d_in, const int* in_sizes, int n_in,
                              void* d_out, int out_size, void* d_ws, size_t ws_size,
                              hipStream_t stream) {
    const float* x = (const float*)d_in[0];
    const float* shift_w = (const float*)d_in[1];
    const float* shift_b = (const float*)d_in[2];
    const float* mod_w = (const float*)d_in[3];
    const float* mod_b = (const float*)d_in[4];
    const float* conv_w = (const float*)d_in[5];
    float* out = (float*)d_out;

    char* ws = (char*)d_ws;
    __half* xTh = (__half*)ws;                         // 4 MB
    __half* xTl = (__half*)(ws + 4194304);             // 4 MB
    __half* xCb = (__half*)(ws + 8388608);             // 4 MB
    __half* WtF = (__half*)(ws + 12582912);            // 144 KB
    __half* WtSFh = (__half*)(ws + 12730368);          // 36 KB
    __half* WtSFl = (__half*)(ws + 12767232);          // 36 KB  (total 12.8 MB)

    k_pre<<<dim3(872), dim3(256), 0, stream>>>(x, conv_w, shift_w, mod_w,
                                               xTh, xTl, xCb, WtF, WtSFh, WtSFl);
    k_fused<<<dim3(512), dim3(512), 0, stream>>>(xTh, xTl, xCb, WtF, WtSFh,
                                                 WtSFl, shift_b, mod_b, out);
}

// Round 14
// 34.851 us; speedup vs baseline: 2.8548x; 1.0459x over previous
//
#include <hip/hip_runtime.h>
#include <hip/hip_fp16.h>
#include <math.h>

// B=8, C=64, H=W=64, O=128, K=3, N=9, stride=1, pad=1
// ws layout (12.8 MB):
//   xTh   @ 0         : fp16 hi(x)  [8][4096 pix][64 c] = 4,194,304 B
//   xTl   @ 4194304   : fp16 lo(x)  [8][4096 pix][64 c] = 4,194,304 B
//   xCb   @ 8388608   : fp16 (x[p]+2x[p+1]) [8][4096][64] = 4,194,304 B
//   WtF   @ 12582912  : fp16 main W in MFMA-fragment order  = 147,456 B
//   WtSFh @ 12730368  : fp16 stage1 W hi, fragment order    =  36,864 B
//   WtSFl @ 12767232  : fp16 stage1 W lo, fragment order    =  36,864 B

typedef _Float16 half8_t __attribute__((ext_vector_type(8)));
typedef float f32x4 __attribute__((ext_vector_type(4)));

// ---------------------------------------------------------------------------
// k_pre (R11-verbatim): x -> xTh/xTl/xCb ; W -> fragment-order tables
// ---------------------------------------------------------------------------
__global__ __launch_bounds__(256) void k_pre(const float* __restrict__ x,
                                             const float* __restrict__ cw,
                                             const float* __restrict__ shift_w,
                                             const float* __restrict__ mod_w,
                                             __half* __restrict__ xTh,
                                             __half* __restrict__ xTl,
                                             __half* __restrict__ xCb,
                                             __half* __restrict__ WtF,
                                             __half* __restrict__ WtSFh,
                                             __half* __restrict__ WtSFl) {
    __shared__ float tile[64][65];
    int bid = blockIdx.x;
    int t = threadIdx.x;
    if (bid < 512) {
        int b = bid >> 6, pt = bid & 63;            // pt = image row
        int lane = t & 63, cq = t >> 6;
        const float* xb = x + ((size_t)b << 18);
#pragma unroll
        for (int r = 0; r < 16; ++r) {
            int c = cq * 16 + r;
            tile[c][lane] = xb[((size_t)c << 12) + pt * 64 + lane];
        }
        __syncthreads();
        int p = t >> 2, qc = t & 3;
        __align__(16) _Float16 hh[16];
        __align__(16) _Float16 ll[16];
        __align__(16) _Float16 cb[16];
#pragma unroll
        for (int k = 0; k < 16; ++k) {
            float v0 = tile[qc * 16 + k][p];
            float v1 = (p < 63) ? tile[qc * 16 + k][p + 1] : 0.f;  // col63 unused
            _Float16 h = (_Float16)v0;
            hh[k] = h;
            ll[k] = (_Float16)(v0 - (float)h);
            cb[k] = (_Float16)(v0 + 2.f * v1);      // degenerate bilinear
        }
        size_t off = ((size_t)b << 18) + (size_t)(pt * 64 + p) * 64 + qc * 16;
        ((uint4*)(xTh + off))[0] = ((uint4*)hh)[0];
        ((uint4*)(xTh + off))[1] = ((uint4*)hh)[1];
        ((uint4*)(xTl + off))[0] = ((uint4*)ll)[0];
        ((uint4*)(xTl + off))[1] = ((uint4*)ll)[1];
        ((uint4*)(xCb + off))[0] = ((uint4*)cb)[0];
        ((uint4*)(xCb + off))[1] = ((uint4*)cb)[1];
    } else {
        int u = (bid - 512) * 256 + t;
        if (u < 73728) {
            int e = u & 7, l = (u >> 3) & 63, ks = (u >> 9) & 1;
            int g = (u >> 10) & 3, w = (u >> 12) & 1, n = u >> 13;
            int o = w * 64 + g * 16 + (l & 15);
            int c = ks * 32 + (l >> 4) * 8 + e;
            WtF[u] = __float2half_rn(cw[(o * 64 + c) * 9 + n]);
        } else {
            int q = u - 73728;
            if (q < 18432) {
                int e = q & 7, l = (q >> 3) & 63, nf = (q >> 9) & 1;
                int chf = (q >> 10) & 1, tap = q >> 11;
                int ch = nf * 16 + (l & 15);
                int c = chf * 32 + (l >> 4) * 8 + e;
                float wv = 0.f;
                if (ch < 18) wv = shift_w[(ch * 64 + c) * 9 + tap];
                else if (ch < 27) wv = mod_w[((ch - 18) * 64 + c) * 9 + tap];
                _Float16 h = (_Float16)wv;
                _Float16 lo = (_Float16)(wv - (float)h);
                WtSFh[q] = *(__half*)&h;
                WtSFl[q] = *(__half*)&lo;
            }
        }
    }
}

// ---------------------------------------------------------------------------
// k_fused: block = 64 pixels (one image row) x 128 outputs, 8 waves (512 thr).
//   R13-validated structure; phase B restructured per T14 (issue-early /
//   write-late): tap n+1's W+gather loads issue BEFORE MFMA[n] (LDS-only),
//   hiding the ~300-500cy L2 latency; combine+ds_write after; 1 barrier/tap.
// ---------------------------------------------------------------------------
__global__ __launch_bounds__(512, 2) void k_fused(
    const __half* __restrict__ xTh, const __half* __restrict__ xTl,
    const __half* __restrict__ xCb, const __half* __restrict__ WtF,
    const __half* __restrict__ WtSFh, const __half* __restrict__ WtSFl,
    const float* __restrict__ shift_b, const float* __restrict__ mod_b,
    float* __restrict__ out) {
    // arena: stage: tileH @0 (25344), tileL @25344 (25344)
    //        phase B: A slabs @0,@8192 (8KB each); W slabs @16384,@32768 (16KB each)
    //        epilogue: Ep f32[128][65] @0 (33280), after final tap barrier
    __shared__ __align__(16) unsigned char arena[50688];
    __shared__ float Cw[2][4][16][36];   // [wh][wp][pix16][ch(36)]
    __shared__ uint4 recA[9][64];

    int t = threadIdx.x;
    int l = t & 63;
    int w = t >> 6;                       // 8 waves
    int l15 = l & 15, lhi = l >> 4;

    // XCD swizzle: 512 = 8 XCD x 64; each XCD gets one batch image.
    int bid = blockIdx.x;
    int bk = (bid & 7) * 64 + (bid >> 3);
    int b = bk >> 6;
    int row = bk & 63;

    const __half* xbh = xTh + ((size_t)b << 18);
    const __half* xbl = xTl + ((size_t)b << 18);
    const __half* xbc = xCb + ((size_t)b << 18);

    // ---------------- stage halo tile: 3 rows x 66 cols, h+l ----------------
#pragma unroll
    for (int rr = 0; rr < 7; ++rr) {
        int d = rr * 512 + t;
        if (d < 3168) {
            int bufl = d >= 1584 ? 1 : 0;
            int dd = d - bufl * 1584;
            int s = dd >> 3, cb8 = dd & 7;   // slot s (198), 16B chunk cb8
            int r = s / 66, j = s - r * 66;
            int grow = row + r - 1;
            int gcol = j - 1;
            uint4 v = make_uint4(0u, 0u, 0u, 0u);
            if ((unsigned)grow < 64u && (unsigned)gcol < 64u) {
                const __half* src = (bufl ? xbl : xbh) +
                                    ((size_t)((grow << 6) + gcol) << 6) + (cb8 << 3);
                v = *(const uint4*)src;
            }
            int dst = bufl * 25344 + s * 128 + ((cb8 << 4) ^ ((s & 7) << 4));
            *(uint4*)&arena[dst] = v;
        }
    }
    __syncthreads();

    // ---------------- Phase A: wave (wp = w>>1 in 0..3, wh = w&1) -------------
    {
        int wp = w >> 1, wh = w & 1;
        f32x4 accA[2];
        accA[0] = (f32x4){0.f, 0.f, 0.f, 0.f};
        accA[1] = (f32x4){0.f, 0.f, 0.f, 0.f};
#pragma unroll
        for (int tr = 0; tr < 3; ++tr)
#pragma unroll
            for (int tc = 0; tc < 3; ++tc) {
                int tap = tr * 3 + tc;
                int j = wp * 16 + l15 + tc;      // tile col 0..65
                int s = tr * 66 + j;
                int cbyte = (wh << 6) + (lhi << 4);
                int addr = s * 128 + (cbyte ^ ((s & 7) << 4));
                half8_t Ah = *(const half8_t*)&arena[addr];
                half8_t Al = *(const half8_t*)&arena[25344 + addr];
#pragma unroll
                for (int nf = 0; nf < 2; ++nf) {
                    int fo = ((((tap << 1) + wh) << 1) + nf) << 9;
                    half8_t Bh = *(const half8_t*)(WtSFh + fo + (l << 3));
                    half8_t Bl = *(const half8_t*)(WtSFl + fo + (l << 3));
                    accA[nf] = __builtin_amdgcn_mfma_f32_16x16x32_f16(Ah, Bh, accA[nf], 0, 0, 0);
                    accA[nf] = __builtin_amdgcn_mfma_f32_16x16x32_f16(Ah, Bl, accA[nf], 0, 0, 0);
                    accA[nf] = __builtin_amdgcn_mfma_f32_16x16x32_f16(Al, Bh, accA[nf], 0, 0, 0);
                }
            }
#pragma unroll
        for (int nf = 0; nf < 2; ++nf)
#pragma unroll
            for (int v4 = 0; v4 < 4; ++v4)
                Cw[wh][wp][(lhi << 2) + v4][nf * 16 + l15] = accA[nf][v4];
    }
    __syncthreads();

    // ---------------- records: 64 pix x 9 n (+ simple flag) ----------------
#pragma unroll
    for (int jj0 = 0; jj0 < 2; ++jj0) {
        int rid = jj0 * 512 + t;
        if (rid < 576) {
            int p = rid & 63;
            int n = rid >> 6;
            int wp = p >> 4, pp = p & 15;
            float sx = Cw[0][wp][pp][n] + Cw[1][wp][pp][n];
            float sy = Cw[0][wp][pp][9 + n] + Cw[1][wp][pp][9 + n];
            float sm = Cw[0][wp][pp][18 + n] + Cw[1][wp][pp][18 + n];

            float px = ((sx + shift_b[n]) + (float)(n / 3 - 1)) + (float)(row + 1);
            float py = ((sy + shift_b[9 + n]) + (float)(n % 3 - 1)) + (float)(p + 1);
            float mod = 1.f / (1.f + expf(-(sm + mod_b[n])));

            float fx = floorf(px), fy = floorf(py);
            int ltx = (int)fminf(fmaxf(fx, 0.f), 63.f);
            int lty = (int)fminf(fmaxf(fy, 0.f), 63.f);
            int rbx = (int)fminf(fmaxf(fx + 1.f, 0.f), 63.f);
            int rby = (int)fminf(fmaxf(fy + 1.f, 0.f), 63.f);
            int pxi = (int)fminf(fmaxf(px, 0.f), 63.f);
            int pyi = (int)fminf(fmaxf(py, 0.f), 63.f);

            int g_lt = (1 + ltx - pxi) * (1 + lty - pyi);
            int g_rb = (1 - rbx + pxi) * (1 - rby + pyi);
            int g_lb = (1 + ltx - pxi) * (1 + rby - pyi);
            int g_rt = (1 - rbx + pxi) * (1 - lty + pyi);

            bool simple = (ltx == pxi) && (lty == pyi) && (rbx == pxi + 1) &&
                          (rby == pyi + 1) && (ltx >= 1) && (lty >= 1);

            int qxa[4] = {ltx, rbx, ltx, rbx};
            int qya[4] = {lty, rby, rby, lty};
            int gga[4] = {g_lt, g_rb, g_lb, g_rt};
            unsigned w0 = 0, w1 = 0;
#pragma unroll
            for (int jq = 0; jq < 4; ++jq) {
                bool valid = (qxa[jq] >= 1) && (qya[jq] >= 1);
                unsigned idx = valid ? (unsigned)((qxa[jq] - 1) * 64 + (qya[jq] - 1)) : 0u;
                unsigned gc = valid ? (unsigned)gga[jq] : 0u;   // 0..2
                if (jq < 2) w0 |= idx << (12 * jq); else w1 |= idx << (12 * (jq - 2));
                w0 |= gc << (24 + 2 * jq);
            }
            if (simple) w1 |= 0x80000000u;
            recA[n][p] = make_uint4(w0, w1, __float_as_uint(mod), 0u);
        }
    }
    __syncthreads();

    // ---------------- Phase B: 9 taps, T14 issue-early/write-late ------------
    int wm = w >> 1, wn = w & 1;        // wm 0..3 (pixel 16-group), wn 0..1 (o-half)
    int mA = t >> 3, cg = t & 7;        // A-build task: pixel mA (0..63), c-chunk cg

    f32x4 acc[4];
#pragma unroll
    for (int g = 0; g < 4; ++g) acc[g] = (f32x4){0.f, 0.f, 0.f, 0.f};

    // prologue: stage tap 0 into slab 0 (serial; one-time)
    {
        const uint4* wsrc = (const uint4*)WtF;
        uint4* wdst = (uint4*)&arena[16384];
        wdst[t] = wsrc[t];
        wdst[512 + t] = wsrc[512 + t];

        uint4 rc = recA[0][mA];
        float mod = __uint_as_float(rc.z);
        __align__(16) __half2 a2[4];
        if (rc.y >> 31) {
            int idx = (int)(rc.x & 0xFFF);
            uint4 v = *(const uint4*)(xbc + (idx << 6) + (cg << 3));
            __half mh = __float2half_rn(mod);
            __half2 mm(mh, mh);
            const __half2* vv = (const __half2*)&v;
            a2[0] = __hmul2(mm, vv[0]);
            a2[1] = __hmul2(mm, vv[1]);
            a2[2] = __hmul2(mm, vv[2]);
            a2[3] = __hmul2(mm, vv[3]);
        } else {
            a2[0] = __half2(0, 0); a2[1] = __half2(0, 0);
            a2[2] = __half2(0, 0); a2[3] = __half2(0, 0);
#pragma unroll
            for (int jq = 0; jq < 4; ++jq) {
                int id = (int)((jq < 2 ? (rc.x >> (12 * jq))
                                       : (rc.y >> (12 * (jq - 2)))) & 0xFFF);
                float wf = (float)((rc.x >> (24 + 2 * jq)) & 3) * mod;
                __half2 wh2 = __half2(__float2half_rn(wf), __float2half_rn(wf));
                uint4 v = *(const uint4*)(xbh + (id << 6) + (cg << 3));
                const __half2* vv = (const __half2*)&v;
                a2[0] = __hfma2(wh2, vv[0], a2[0]);
                a2[1] = __hfma2(wh2, vv[1], a2[1]);
                a2[2] = __hfma2(wh2, vv[2], a2[2]);
                a2[3] = __hfma2(wh2, vv[3], a2[3]);
            }
        }
        *(uint4*)&arena[(mA << 7) | ((cg ^ (mA & 7)) << 4)] = *(uint4*)a2;
    }
    __syncthreads();

    for (int n = 0; n < 9; ++n) {
        int sl = n & 1;

        // 1) issue-early: tap n+1's W + gather loads into registers
        uint4 wv0, wv1, rcN;
        uint4 gr0, gr1, gr2, gr3;
        bool simpleN = false;
        if (n < 8) {
            const uint4* wsrc = (const uint4*)(WtF + (n + 1) * 8192);
            wv0 = wsrc[t];
            wv1 = wsrc[512 + t];
            rcN = recA[n + 1][mA];
            simpleN = (rcN.y >> 31) != 0u;
            if (simpleN) {
                gr0 = *(const uint4*)(xbc + ((int)(rcN.x & 0xFFF) << 6) + (cg << 3));
            } else {
                gr0 = *(const uint4*)(xbh + ((int)(rcN.x & 0xFFF) << 6) + (cg << 3));
                gr1 = *(const uint4*)(xbh + ((int)((rcN.x >> 12) & 0xFFF) << 6) + (cg << 3));
                gr2 = *(const uint4*)(xbh + ((int)(rcN.y & 0xFFF) << 6) + (cg << 3));
                gr3 = *(const uint4*)(xbh + ((int)((rcN.y >> 12) & 0xFFF) << 6) + (cg << 3));
            }
        }

        // 2) MFMA tap n (LDS-only; prefetched VMEM stays in flight)
        {
            const unsigned char* wsl = &arena[16384 + (sl << 14)];
#pragma unroll
            for (int ks = 0; ks < 2; ++ks) {
                int rowa = wm * 16 + l15;
                int gr = (ks * 4 + lhi) ^ (rowa & 7);
                half8_t Af = *(const half8_t*)&arena[(sl << 13) | (rowa << 7) | (gr << 4)];
#pragma unroll
                for (int g = 0; g < 4; ++g) {
                    half8_t Bf = *(const half8_t*)&wsl[((((wn << 2) + g) << 1) + ks) * 1024 +
                                                       (l << 4)];
                    acc[g] = __builtin_amdgcn_mfma_f32_16x16x32_f16(Af, Bf, acc[g], 0, 0, 0);
                }
            }
        }

        // 3) write-late: combine + ds_write tap n+1 into slab sl^1
        if (n < 8) {
            int s2 = sl ^ 1;
            uint4* wdst = (uint4*)&arena[16384 + (s2 << 14)];
            wdst[t] = wv0;
            wdst[512 + t] = wv1;

            float mod = __uint_as_float(rcN.z);
            __align__(16) __half2 a2[4];
            if (simpleN) {
                __half mh = __float2half_rn(mod);
                __half2 mm(mh, mh);
                const __half2* vv = (const __half2*)&gr0;
                a2[0] = __hmul2(mm, vv[0]);
                a2[1] = __hmul2(mm, vv[1]);
                a2[2] = __hmul2(mm, vv[2]);
                a2[3] = __hmul2(mm, vv[3]);
            } else {
                a2[0] = __half2(0, 0); a2[1] = __half2(0, 0);
                a2[2] = __half2(0, 0); a2[3] = __half2(0, 0);
                const uint4* grs[4] = {&gr0, &gr1, &gr2, &gr3};
#pragma unroll
                for (int jq = 0; jq < 4; ++jq) {
                    float wf = (float)((rcN.x >> (24 + 2 * jq)) & 3) * mod;
                    __half2 wh2 = __half2(__float2half_rn(wf), __float2half_rn(wf));
                    const __half2* vv = (const __half2*)grs[jq];
                    a2[0] = __hfma2(wh2, vv[0], a2[0]);
                    a2[1] = __hfma2(wh2, vv[1], a2[1]);
                    a2[2] = __hfma2(wh2, vv[2], a2[2]);
                    a2[3] = __hfma2(wh2, vv[3], a2[3]);
                }
            }
            *(uint4*)&arena[(s2 << 13) | (mA << 7) | ((cg ^ (mA & 7)) << 4)] =
                *(uint4*)a2;
        }
        __syncthreads();
    }

    // ---------------- Epilogue: one-shot Ep f32[128][65] ----------------
    // (loop-final barrier already synchronized all MFMA reads of the arena)
    float* Ep = (float*)arena;
#pragma unroll
    for (int g = 0; g < 4; ++g) {
        int o_loc = (wn << 6) + (g << 4) + l15;
#pragma unroll
        for (int v4 = 0; v4 < 4; ++v4)
            Ep[o_loc * 65 + (wm << 4) + (lhi << 2) + v4] = acc[g][v4];
    }
    __syncthreads();
    {
        float* ob = out + ((size_t)b << 19);
        int prow = row << 6;
#pragma unroll
        for (int r = 0; r < 4; ++r) {
            int o_loc = (r << 5) + (t >> 4);   // 0..127
            int mseg = t & 15;                 // 0..15 -> 64 pix
            float4 fa;
            fa.x = Ep[o_loc * 65 + mseg * 4 + 0];
            fa.y = Ep[o_loc * 65 + mseg * 4 + 1];
            fa.z = Ep[o_loc * 65 + mseg * 4 + 2];
            fa.w = Ep[o_loc * 65 + mseg * 4 + 3];
            float* dst = ob + (((size_t)o_loc) << 12) + prow + mseg * 4;
            *(float4*)dst = fa;
        }
    }
}

// ---------------------------------------------------------------------------
extern "C" void kernel_launch(void* const* d_in, const int* in_sizes, int n_in,
                              void* d_out, int out_size, void* d_ws, size_t ws_size,
                              hipStream_t stream) {
    const float* x = (const float*)d_in[0];
    const float* shift_w = (const float*)d_in[1];
    const float* shift_b = (const float*)d_in[2];
    const float* mod_w = (const float*)d_in[3];
    const float* mod_b = (const float*)d_in[4];
    const float* conv_w = (const float*)d_in[5];
    float* out = (float*)d_out;

    char* ws = (char*)d_ws;
    __half* xTh = (__half*)ws;                         // 4 MB
    __half* xTl = (__half*)(ws + 4194304);             // 4 MB
    __half* xCb = (__half*)(ws + 8388608);             // 4 MB
    __half* WtF = (__half*)(ws + 12582912);            // 144 KB
    __half* WtSFh = (__half*)(ws + 12730368);          // 36 KB
    __half* WtSFl = (__half*)(ws + 12767232);          // 36 KB  (total 12.8 MB)

    k_pre<<<dim3(872), dim3(256), 0, stream>>>(x, conv_w, shift_w, mod_w,
                                               xTh, xTl, xCb, WtF, WtSFh, WtSFl);
    k_fused<<<dim3(512), dim3(512), 0, stream>>>(xTh, xTl, xCb, WtF, WtSFh,
                                                 WtSFl, shift_b, mod_b, out);
}